// Round 5
// baseline (345.473 us; speedup 1.0000x reference)
//
#include <hip/hip_runtime.h>
#include <cstddef>
#include <cstdint>

#define SQ    1023
#define HIDC  2048
#define NQC   10240
#define NKVC  1024

typedef unsigned short ushort_t;
typedef __bf16 bf16x8 __attribute__((ext_vector_type(8)));
typedef float  f32x4  __attribute__((ext_vector_type(4)));

__device__ __forceinline__ ushort_t f2bf(float x) {
  union { float f; uint32_t u; } v; v.f = x;
  uint32_t r = v.u + 0x7fffu + ((v.u >> 16) & 1u);   // RNE
  return (ushort_t)(r >> 16);
}

// ======================= RoPE tables =======================
__global__ void k_tables(float* __restrict__ cosT, float* __restrict__ sinT) {
  int idx = blockIdx.x * blockDim.x + threadIdx.x;
  if (idx >= SQ * 64) return;
  int t = idx >> 6, i = idx & 63;
  float inv = powf(10000.0f, -(float)i * (1.0f / 64.0f));
  float f = (float)t * inv;
  cosT[idx] = cosf(f);
  sinT[idx] = sinf(f);
}

// ======================= RoPE + scale + bf16 (Q), sums up to 2 partials ====
__global__ void k_rope_q(const float* __restrict__ qa, const float* __restrict__ qb2,
                         int nPart, ushort_t* __restrict__ qb,
                         const float* __restrict__ cosT, const float* __restrict__ sinT) {
  int idx = blockIdx.x * blockDim.x + threadIdx.x;
  if (idx >= 5115 * 16 * 64) return;
  int d  = idx & 63;
  int h  = (idx >> 6) & 15;
  int st = idx >> 10;            // g*1023 + t
  int t  = st % 1023;
  size_t base = (((size_t)st * 16) + h) * 128 + d;
  float x0 = qa[base], x1 = qa[base + 64];
  if (nPart > 1) { x0 += qb2[base]; x1 += qb2[base + 64]; }
  float c = cosT[t * 64 + d], s = sinT[t * 64 + d];
  const float sc = 0.08838834764831845f;   // 1/sqrt(128)
  qb[base]      = f2bf((x0 * c - x1 * s) * sc);
  qb[base + 64] = f2bf((x1 * c + x0 * s) * sc);
}

// ======================= RoPE + bf16 (K), sums 4 split-K partials =======
__global__ void k_rope_k(const float* __restrict__ kvp, ushort_t* __restrict__ kb,
                         const float* __restrict__ cosT, const float* __restrict__ sinT) {
  int idx = blockIdx.x * blockDim.x + threadIdx.x;
  if (idx >= SQ * 4 * 64) return;
  int d   = idx & 63;
  int kvh = (idx >> 6) & 3;
  int t   = idx >> 8;
  size_t src = (size_t)t * 1024 + kvh * 128 + d;
  float x0 = 0.f, x1 = 0.f;
  #pragma unroll
  for (int z = 0; z < 4; ++z) {
    x0 += kvp[(size_t)z * (SQ * 1024) + src];
    x1 += kvp[(size_t)z * (SQ * 1024) + src + 64];
  }
  float c = cosT[t * 64 + d], s = sinT[t * 64 + d];
  size_t dst = (size_t)t * 512 + kvh * 128 + d;
  kb[dst]      = f2bf(x0 * c - x1 * s);
  kb[dst + 64] = f2bf(x1 * c + x0 * s);
}

// ======================= V transpose (sums 4 partials) =======================
__global__ __launch_bounds__(256)
void k_vtrans(const float* __restrict__ kvp, ushort_t* __restrict__ vt) {
  __shared__ float tile[32][33];
  int v0 = blockIdx.x * 32;
  int t0 = blockIdx.y * 32;
  int r = threadIdx.x >> 5, c = threadIdx.x & 31;
  #pragma unroll
  for (int p = 0; p < 4; ++p) {
    int t = t0 + p * 8 + r;
    float s = 0.f;
    if (t < SQ) {
      size_t src = (size_t)t * 1024 + 512 + v0 + c;
      #pragma unroll
      for (int z = 0; z < 4; ++z) s += kvp[(size_t)z * (SQ * 1024) + src];
    }
    tile[p * 8 + r][c] = s;
  }
  __syncthreads();
  #pragma unroll
  for (int p = 0; p < 4; ++p) {
    int v = v0 + p * 8 + r;
    vt[(size_t)v * 1024 + t0 + c] = f2bf(tile[c][p * 8 + r]);
  }
}

// ======================= f32 -> bf16 convert =======================
__global__ void k_f2b(const float* __restrict__ in, ushort_t* __restrict__ out, int n) {
  int i = (blockIdx.x * blockDim.x + threadIdx.x) * 4;
  if (i >= n) return;
  float4 v = *reinterpret_cast<const float4*>(in + i);
  uint2 pk;
  pk.x = (uint32_t)f2bf(v.x) | ((uint32_t)f2bf(v.y) << 16);
  pk.y = (uint32_t)f2bf(v.z) | ((uint32_t)f2bf(v.w) << 16);
  *reinterpret_cast<uint2*>(out + i) = pk;
}

// akv[r][c] = bf16( c<2048 ? prevh[r][c] : hidden[r][c-2048] )
__global__ void k_concat_b(const float* __restrict__ prevh, const float* __restrict__ hidden,
                           ushort_t* __restrict__ out) {
  int i = (blockIdx.x * blockDim.x + threadIdx.x) * 4;
  if (i >= SQ * 4096) return;
  int r = i >> 12, c = i & 4095;
  const float* src = (c < 2048) ? (prevh + (size_t)r * 2048 + c)
                                : (hidden + (size_t)r * 2048 + (c - 2048));
  float4 v = *reinterpret_cast<const float4*>(src);
  uint2 pk;
  pk.x = (uint32_t)f2bf(v.x) | ((uint32_t)f2bf(v.y) << 16);
  pk.y = (uint32_t)f2bf(v.z) | ((uint32_t)f2bf(v.w) << 16);
  *reinterpret_cast<uint2*>(out + (size_t)r * 4096 + c) = pk;
}

// ======================= transpose + convert: W [K][N] f32 -> Wt [N][K] bf16 ======
__global__ __launch_bounds__(256)
void k_tconv(const float* __restrict__ in, ushort_t* __restrict__ out, int K, int N) {
  __shared__ float t[32][33];
  int n0 = blockIdx.x * 32, k0 = blockIdx.y * 32;
  int r = threadIdx.x >> 5, c = threadIdx.x & 31;
  #pragma unroll
  for (int p = 0; p < 4; ++p)
    t[p * 8 + r][c] = in[(size_t)(k0 + p * 8 + r) * N + n0 + c];
  __syncthreads();
  #pragma unroll
  for (int p = 0; p < 4; ++p)
    out[(size_t)(n0 + p * 8 + r) * K + k0 + c] = f2bf(t[c][p * 8 + r]);
}

// ======================= bf16 MFMA GEMM, 128x128 tile, BK=64, swizzled LDS ===
// C[M][N] f32 = A[M][Kd] @ Bt[N][Kd] bf16. 4 waves (2x2), wave = 64x64 (4x4 frags).
// Split-K: blockIdx.z selects K-range [z*kLen, +kLen) and output C0 (z=0) / C1 (z=1).
// LDS rows are 64 bf16 = 8 16-B slots; slot s of row r holds data slot s^(r&7)
// (pre-swizzled global source, linear LDS dest, swizzled frag read).
__global__ __launch_bounds__(256)
void k_gemm128(const ushort_t* __restrict__ A, const ushort_t* __restrict__ Bt,
               float* __restrict__ C0, float* __restrict__ C1,
               int M, int N, int Kd, int kLen)
{
  __shared__ __align__(16) ushort_t As[128 * 64];
  __shared__ __align__(16) ushort_t Bs[128 * 64];

  const int tid  = threadIdx.x;
  const int lane = tid & 63;
  const int w    = tid >> 6;
  const int wm   = w >> 1, wn = w & 1;
  const int fr   = lane & 15;            // frag row (A) / col (B)
  const int kg   = lane >> 4;            // k-group 0..3
  const int m0   = blockIdx.y * 128, n0 = blockIdx.x * 128;
  const int kOff = blockIdx.z * kLen;
  float* C = (blockIdx.z == 0) ? C0 : C1;

  f32x4 acc[4][4];
  #pragma unroll
  for (int i = 0; i < 4; ++i)
    #pragma unroll
    for (int j = 0; j < 4; ++j) acc[i][j] = (f32x4){0.f, 0.f, 0.f, 0.f};

  for (int k0 = kOff; k0 < kOff + kLen; k0 += 64) {
    // stage A,B tiles (each 128 rows x 64 k = 16 KB), 4+4 gloads/thread
    #pragma unroll
    for (int i = 0; i < 4; ++i) {
      int s    = i * 256 + tid;          // 16-B slot index 0..1023
      int row  = s >> 3;
      int col8 = (s & 7) ^ (row & 7);    // pre-swizzled source slot
      const ushort_t* ga = A  + (size_t)(m0 + row) * Kd + k0 + col8 * 8;
      const ushort_t* gb = Bt + (size_t)(n0 + row) * Kd + k0 + col8 * 8;
      int lo = (i * 256 + w * 64) * 8;   // wave-uniform LDS base (ushorts)
      __builtin_amdgcn_global_load_lds(
          (const __attribute__((address_space(1))) void*)ga,
          (__attribute__((address_space(3))) void*)(As + lo), 16, 0, 0);
      __builtin_amdgcn_global_load_lds(
          (const __attribute__((address_space(1))) void*)gb,
          (__attribute__((address_space(3))) void*)(Bs + lo), 16, 0, 0);
    }
    __syncthreads();

    #pragma unroll
    for (int kk = 0; kk < 2; ++kk) {
      bf16x8 av[4], bv[4];
      int csl = ((kk * 4 + kg) ^ (fr & 7)) << 3;   // swizzled col slot (ushorts)
      #pragma unroll
      for (int mi = 0; mi < 4; ++mi)
        av[mi] = *reinterpret_cast<const bf16x8*>(As + (wm * 64 + mi * 16 + fr) * 64 + csl);
      #pragma unroll
      for (int nj = 0; nj < 4; ++nj)
        bv[nj] = *reinterpret_cast<const bf16x8*>(Bs + (wn * 64 + nj * 16 + fr) * 64 + csl);
      #pragma unroll
      for (int mi = 0; mi < 4; ++mi)
        #pragma unroll
        for (int nj = 0; nj < 4; ++nj)
          acc[mi][nj] = __builtin_amdgcn_mfma_f32_16x16x32_bf16(av[mi], bv[nj], acc[mi][nj], 0, 0, 0);
    }
    __syncthreads();
  }

  // C/D layout: col = lane&15, row = (lane>>4)*4 + r
  #pragma unroll
  for (int mi = 0; mi < 4; ++mi) {
    #pragma unroll
    for (int nj = 0; nj < 4; ++nj) {
      int rbase = m0 + wm * 64 + mi * 16 + kg * 4;
      int col   = n0 + wn * 64 + nj * 16 + fr;
      #pragma unroll
      for (int r = 0; r < 4; ++r) {
        int gr = rbase + r;
        if (gr < M) C[(size_t)gr * N + col] = acc[mi][nj][r];
      }
    }
  }
}

// ======================= bf16 MFMA GEMM, 64x128 tile (GEMM2 split-K) =========
__global__ __launch_bounds__(256)
void k_gemm64(const ushort_t* __restrict__ A, const ushort_t* __restrict__ Bt,
              float* __restrict__ C, int M, int N, int Kd, int kLen)
{
  __shared__ __align__(16) ushort_t As[64 * 32];
  __shared__ __align__(16) ushort_t Bs[128 * 32];

  const int tid  = threadIdx.x;
  const int lane = tid & 63;
  const int w    = tid >> 6;
  const int wm   = w >> 1, wn = w & 1;
  const int fr   = lane & 15;
  const int kg   = (lane >> 4) * 8;
  const int g4   = lane >> 4;
  const int l15  = lane & 15;
  const int m0   = blockIdx.y * 64, n0 = blockIdx.x * 128;
  const int kOff = blockIdx.z * kLen;
  C += (size_t)blockIdx.z * M * N;

  const int arow = tid >> 2, aslot = (tid & 3) * 8;

  f32x4 acc[2][4];
  #pragma unroll
  for (int i = 0; i < 2; ++i)
    #pragma unroll
    for (int j = 0; j < 4; ++j) acc[i][j] = (f32x4){0.f, 0.f, 0.f, 0.f};

  for (int k0 = kOff; k0 < kOff + kLen; k0 += 32) {
    {
      const ushort_t* ga = A + (size_t)(m0 + arow) * Kd + k0 + aslot;
      __builtin_amdgcn_global_load_lds(
          (const __attribute__((address_space(1))) void*)ga,
          (__attribute__((address_space(3))) void*)(As + w * 512), 16, 0, 0);
    }
    #pragma unroll
    for (int c = 0; c < 2; ++c) {
      int u = c * 256 + tid;
      const ushort_t* gb = Bt + (size_t)(n0 + (u >> 2)) * Kd + k0 + (u & 3) * 8;
      __builtin_amdgcn_global_load_lds(
          (const __attribute__((address_space(1))) void*)gb,
          (__attribute__((address_space(3))) void*)(Bs + (c * 256 + w * 64) * 8), 16, 0, 0);
    }
    __syncthreads();

    bf16x8 av[2], bv[4];
    #pragma unroll
    for (int mi = 0; mi < 2; ++mi)
      av[mi] = *reinterpret_cast<const bf16x8*>(As + (wm * 32 + mi * 16 + fr) * 32 + kg);
    #pragma unroll
    for (int nj = 0; nj < 4; ++nj)
      bv[nj] = *reinterpret_cast<const bf16x8*>(Bs + (wn * 64 + nj * 16 + fr) * 32 + kg);
    #pragma unroll
    for (int mi = 0; mi < 2; ++mi)
      #pragma unroll
      for (int nj = 0; nj < 4; ++nj)
        acc[mi][nj] = __builtin_amdgcn_mfma_f32_16x16x32_bf16(av[mi], bv[nj], acc[mi][nj], 0, 0, 0);
    __syncthreads();
  }

  #pragma unroll
  for (int mi = 0; mi < 2; ++mi) {
    #pragma unroll
    for (int nj = 0; nj < 4; ++nj) {
      int rbase = m0 + wm * 32 + mi * 16 + g4 * 4;
      int col   = n0 + wn * 64 + nj * 16 + l15;
      #pragma unroll
      for (int r = 0; r < 4; ++r) {
        int gr = rbase + r;
        if (gr < M) C[(size_t)gr * N + col] = acc[mi][nj][r];
      }
    }
  }
}

// ======================= MFMA flash attention =======================
__global__ __launch_bounds__(256)
void k_attn_mfma(const ushort_t* __restrict__ qb, const ushort_t* __restrict__ kb,
                 const ushort_t* __restrict__ vt, ushort_t* __restrict__ oattb)
{
  __shared__ __align__(16) ushort_t Ks[64 * 128];
  __shared__ __align__(16) ushort_t Vs[128 * 64];
  __shared__ __align__(16) ushort_t Ps[4][16 * 64];

  const int tid  = threadIdx.x;
  const int lane = tid & 63;
  const int w    = tid >> 6;
  const int l15  = lane & 15;
  const int g4   = lane >> 4;
  const int gh   = blockIdx.x;
  const int g = gh >> 4, h = gh & 15, kvh = (gh & 15) >> 2;
  const int qt = 15 - blockIdx.y;
  const int t0 = qt * 64;

  bf16x8 av[4];
  {
    int t = t0 + w * 16 + l15;
    const ushort_t* qrow = qb + (((size_t)(g * SQ + t)) * 16 + h) * 128;
    #pragma unroll
    for (int kk = 0; kk < 4; ++kk)
      av[kk] = *reinterpret_cast<const bf16x8*>(qrow + kk * 32 + g4 * 8);
  }

  f32x4 acc[8];
  #pragma unroll
  for (int dt = 0; dt < 8; ++dt) acc[dt] = (f32x4){0.f, 0.f, 0.f, 0.f};
  float m[4], l[4];
  #pragma unroll
  for (int r = 0; r < 4; ++r) { m[r] = -1e30f; l[r] = 0.f; }

  ushort_t* pw = &Ps[w][0];

  for (int jt = 0; jt <= qt; ++jt) {
    int u0 = jt * 64;
    #pragma unroll
    for (int i = 0; i < 4; ++i) {
      int c = (w * 4 + i) * 64 + lane;
      int kv = c >> 4, sl = c & 15;
      const ushort_t* srck = kb + (size_t)(u0 + kv) * 512 + kvh * 128 + ((sl ^ (kv & 7)) << 3);
      __builtin_amdgcn_global_load_lds(
          (const __attribute__((address_space(1))) void*)srck,
          (__attribute__((address_space(3))) void*)(Ks + (w * 4 + i) * 512), 16, 0, 0);
      int d = c >> 3, sv = c & 7;
      const ushort_t* srcv = vt + (size_t)(kvh * 128 + d) * 1024 + u0 + ((sv ^ (d & 7)) << 3);
      __builtin_amdgcn_global_load_lds(
          (const __attribute__((address_space(1))) void*)srcv,
          (__attribute__((address_space(3))) void*)(Vs + (w * 4 + i) * 512), 16, 0, 0);
    }
    __syncthreads();

    f32x4 S[4];
    #pragma unroll
    for (int ct = 0; ct < 4; ++ct) S[ct] = (f32x4){0.f, 0.f, 0.f, 0.f};
    __builtin_amdgcn_s_setprio(1);
    #pragma unroll
    for (int ct = 0; ct < 4; ++ct) {
      int kv = ct * 16 + l15;
      #pragma unroll
      for (int kk = 0; kk < 4; ++kk) {
        bf16x8 bv = *reinterpret_cast<const bf16x8*>(
            Ks + kv * 128 + ((((kk << 2) | g4) ^ (kv & 7)) << 3));
        S[ct] = __builtin_amdgcn_mfma_f32_16x16x32_bf16(av[kk], bv, S[ct], 0, 0, 0);
      }
    }
    __builtin_amdgcn_s_setprio(0);
    if (jt == qt) {
      #pragma unroll
      for (int ct = 0; ct < 4; ++ct) {
        int u = u0 + ct * 16 + l15;
        #pragma unroll
        for (int r = 0; r < 4; ++r) {
          int t = t0 + w * 16 + g4 * 4 + r;
          if (u > t) S[ct][r] = -1e30f;
        }
      }
    }
    float corr[4];
    #pragma unroll
    for (int r = 0; r < 4; ++r) {
      float tm = fmaxf(fmaxf(S[0][r], S[1][r]), fmaxf(S[2][r], S[3][r]));
      tm = fmaxf(tm, __shfl_xor(tm, 1));
      tm = fmaxf(tm, __shfl_xor(tm, 2));
      tm = fmaxf(tm, __shfl_xor(tm, 4));
      tm = fmaxf(tm, __shfl_xor(tm, 8));
      float mn = fmaxf(m[r], tm);
      corr[r] = __expf(m[r] - mn);
      m[r] = mn;
      float ps = 0.f;
      #pragma unroll
      for (int ct = 0; ct < 4; ++ct) {
        float p = __expf(S[ct][r] - mn);
        S[ct][r] = p;
        ps += p;
      }
      ps += __shfl_xor(ps, 1);
      ps += __shfl_xor(ps, 2);
      ps += __shfl_xor(ps, 4);
      ps += __shfl_xor(ps, 8);
      l[r] = l[r] * corr[r] + ps;
    }
    #pragma unroll
    for (int dt = 0; dt < 8; ++dt)
      #pragma unroll
      for (int r = 0; r < 4; ++r) acc[dt][r] *= corr[r];

    #pragma unroll
    for (int ct = 0; ct < 4; ++ct) {
      int kv = ct * 16 + l15;
      #pragma unroll
      for (int r = 0; r < 4; ++r) {
        int q = g4 * 4 + r;
        pw[q * 64 + ((((kv >> 3) ^ (q & 7)) << 3) | (kv & 7))] = f2bf(S[ct][r]);
      }
    }
    __builtin_amdgcn_s_setprio(1);
    #pragma unroll
    for (int kk = 0; kk < 2; ++kk) {
      bf16x8 pa = *reinterpret_cast<const bf16x8*>(
          pw + l15 * 64 + ((((kk << 2) | g4) ^ (l15 & 7)) << 3));
      #pragma unroll
      for (int dt = 0; dt < 8; ++dt) {
        int d = dt * 16 + l15;
        bf16x8 vv = *reinterpret_cast<const bf16x8*>(
            Vs + d * 64 + ((((kk << 2) | g4) ^ (d & 7)) << 3));
        acc[dt] = __builtin_amdgcn_mfma_f32_16x16x32_bf16(pa, vv, acc[dt], 0, 0, 0);
      }
    }
    __builtin_amdgcn_s_setprio(0);
    __syncthreads();
  }

  #pragma unroll
  for (int r = 0; r < 4; ++r) {
    int t = t0 + w * 16 + g4 * 4 + r;
    if (t >= SQ) continue;
    float inv = 1.f / l[r];
    ushort_t* dst = oattb + ((size_t)(g * SQ + t)) * 2048 + h * 128;
    #pragma unroll
    for (int dt = 0; dt < 8; ++dt)
      dst[dt * 16 + l15] = f2bf(acc[dt][r] * inv);
  }
}

// ======================= launch =======================
extern "C" void kernel_launch(void* const* d_in, const int* in_sizes, int n_in,
                              void* d_out, int out_size, void* d_ws, size_t ws_size,
                              hipStream_t stream) {
  const float* hidden = (const float*)d_in[0];   // (1024, 2048)
  const float* prevh  = (const float*)d_in[1];   // (1023, 2048)
  const float* Wq     = (const float*)d_in[4];   // (2048, 10240)
  const float* Wkv    = (const float*)d_in[5];   // (4096, 1024)
  const float* Wo     = (const float*)d_in[6];   // (2048, 2048)
  float* out = (float*)d_out;                    // (5115, 2048)

  char* ws = (char*)d_ws;
  char* ws0 = ws;
  float*    kvp   = (float*)ws;                        ws += (size_t)4 * SQ * 1024 * 4;
  float*    cosT  = (float*)ws;                        ws += (size_t)65472 * 4;
  float*    sinT  = (float*)ws;                        ws += (size_t)65472 * 4;
  ushort_t* qbb   = (ushort_t*)ws;                     ws += (size_t)5120 * 2048 * 2;
  ushort_t* kb    = (ushort_t*)ws;                     ws += (size_t)1024 * 512 * 2;
  ushort_t* vtb   = (ushort_t*)ws;                     ws += (size_t)512 * 1024 * 2;
  ushort_t* hbf   = (ushort_t*)ws;                     ws += (size_t)1024 * 2048 * 2;
  ushort_t* akv   = (ushort_t*)ws;                     ws += (size_t)1024 * 4096 * 2;
  ushort_t* oattb = (ushort_t*)ws;                     ws += (size_t)5120 * 2048 * 2;
  ushort_t* wqt   = (ushort_t*)ws;                     ws += (size_t)10240 * 2048 * 2;
  ushort_t* wkvt  = (ushort_t*)ws;                     ws += (size_t)1024 * 4096 * 2;
  ushort_t* wot   = (ushort_t*)ws;                     ws += (size_t)2048 * 2048 * 2;
  float*    qp2   = (float*)ws;                        ws += (size_t)SQ * 10240 * 4;

  // split-K x2 for GEMM1 only if the workspace is large enough for partial 2
  const int zq = (ws_size >= (size_t)(ws - ws0)) ? 2 : 1;

  float* qp = out;   // f32 q_proj partial 0 lives in d_out (exact fit)

  k_tables<<<dim3((SQ * 64 + 255) / 256), dim3(256), 0, stream>>>(cosT, sinT);

  // weight transpose+convert
  k_tconv<<<dim3(NQC / 32, HIDC / 32), dim3(256), 0, stream>>>(Wq, wqt, HIDC, NQC);
  k_tconv<<<dim3(NKVC / 32, 4096 / 32), dim3(256), 0, stream>>>(Wkv, wkvt, 4096, NKVC);
  k_tconv<<<dim3(HIDC / 32, HIDC / 32), dim3(256), 0, stream>>>(Wo, wot, HIDC, HIDC);

  // A-matrix converts
  k_f2b<<<dim3((SQ * 2048 / 4 + 255) / 256), dim3(256), 0, stream>>>(hidden + 2048, hbf, SQ * 2048);
  k_concat_b<<<dim3((SQ * 4096 / 4 + 255) / 256), dim3(256), 0, stream>>>(prevh, hidden, akv);

  // q_proj = hidden[1:] @ Wq   (128^2 tile BK=64, split-K x zq -> 640*zq blocks)
  k_gemm128<<<dim3(NQC / 128, 8, zq), dim3(256), 0, stream>>>(
      hbf, wqt, qp, qp2, SQ, NQC, 2048, 2048 / zq);
  // kv = concat(prev,hidden) @ Wkv, split-K x4 (512 blocks)
  k_gemm64<<<dim3(NKVC / 128, 16, 4), dim3(256), 0, stream>>>(akv, wkvt, kvp, SQ, NKVC, 4096, 1024);

  // rope + bf16 pack (rope_q folds GEMM1 partials, rope_k/vtrans fold GEMM2 partials)
  k_rope_q<<<dim3((5115 * 16 * 64 + 255) / 256), dim3(256), 0, stream>>>(qp, qp2, zq, qbb, cosT, sinT);
  k_rope_k<<<dim3((SQ * 4 * 64 + 255) / 256), dim3(256), 0, stream>>>(kvp, kb, cosT, sinT);
  k_vtrans<<<dim3(16, 32), dim3(256), 0, stream>>>(kvp, vtb);

  // MFMA flash attention -> bf16 O
  k_attn_mfma<<<dim3(80, 16), dim3(256), 0, stream>>>(qbb, kb, vtb, oattb);

  // out = O_att @ Wo   (128^2 tile BK=64, 640 blocks)
  k_gemm128<<<dim3(HIDC / 128, 40, 1), dim3(256), 0, stream>>>(
      oattb, wot, out, out, 5115, HIDC, 2048, 2048);
}

// Round 6
// 282.554 us; speedup vs baseline: 1.2227x; 1.2227x over previous
//
#include <hip/hip_runtime.h>
#include <cstddef>
#include <cstdint>

#define SQ    1023
#define HIDC  2048
#define NQC   10240
#define NKVC  1024

typedef unsigned short ushort_t;
typedef __bf16 bf16x8 __attribute__((ext_vector_type(8)));
typedef float  f32x4  __attribute__((ext_vector_type(4)));

__device__ __forceinline__ ushort_t f2bf(float x) {
  union { float f; uint32_t u; } v; v.f = x;
  uint32_t r = v.u + 0x7fffu + ((v.u >> 16) & 1u);   // RNE
  return (ushort_t)(r >> 16);
}

// native f32->bf16 (compiler emits packed cvt; RNE) — hot paths only
__device__ __forceinline__ ushort_t f2bf_fast(float x) {
  __bf16 b = (__bf16)x;
  return __builtin_bit_cast(ushort_t, b);
}

// ======================= RoPE tables =======================
__global__ void k_tables(float* __restrict__ cosT, float* __restrict__ sinT) {
  int idx = blockIdx.x * blockDim.x + threadIdx.x;
  if (idx >= SQ * 64) return;
  int t = idx >> 6, i = idx & 63;
  float inv = powf(10000.0f, -(float)i * (1.0f / 64.0f));
  float f = (float)t * inv;
  cosT[idx] = cosf(f);
  sinT[idx] = sinf(f);
}

// ======================= RoPE + scale + bf16 (Q) =======================
__global__ void k_rope_q(const float* __restrict__ q, ushort_t* __restrict__ qb,
                         const float* __restrict__ cosT, const float* __restrict__ sinT) {
  int idx = blockIdx.x * blockDim.x + threadIdx.x;
  if (idx >= 5115 * 16 * 64) return;
  int d  = idx & 63;
  int h  = (idx >> 6) & 15;
  int st = idx >> 10;            // g*1023 + t
  int t  = st % 1023;
  size_t base = (((size_t)st * 16) + h) * 128 + d;
  float x0 = q[base], x1 = q[base + 64];
  float c = cosT[t * 64 + d], s = sinT[t * 64 + d];
  const float sc = 0.08838834764831845f;   // 1/sqrt(128)
  qb[base]      = f2bf((x0 * c - x1 * s) * sc);
  qb[base + 64] = f2bf((x1 * c + x0 * s) * sc);
}

// ======================= RoPE + bf16 (K), sums 4 split-K partials =======
__global__ void k_rope_k(const float* __restrict__ kvp, ushort_t* __restrict__ kb,
                         const float* __restrict__ cosT, const float* __restrict__ sinT) {
  int idx = blockIdx.x * blockDim.x + threadIdx.x;
  if (idx >= SQ * 4 * 64) return;
  int d   = idx & 63;
  int kvh = (idx >> 6) & 3;
  int t   = idx >> 8;
  size_t src = (size_t)t * 1024 + kvh * 128 + d;
  float x0 = 0.f, x1 = 0.f;
  #pragma unroll
  for (int z = 0; z < 4; ++z) {
    x0 += kvp[(size_t)z * (SQ * 1024) + src];
    x1 += kvp[(size_t)z * (SQ * 1024) + src + 64];
  }
  float c = cosT[t * 64 + d], s = sinT[t * 64 + d];
  size_t dst = (size_t)t * 512 + kvh * 128 + d;
  kb[dst]      = f2bf(x0 * c - x1 * s);
  kb[dst + 64] = f2bf(x1 * c + x0 * s);
}

// ======================= V transpose (sums 4 partials) =======================
__global__ __launch_bounds__(256)
void k_vtrans(const float* __restrict__ kvp, ushort_t* __restrict__ vt) {
  __shared__ float tile[32][33];
  int v0 = blockIdx.x * 32;
  int t0 = blockIdx.y * 32;
  int r = threadIdx.x >> 5, c = threadIdx.x & 31;
  #pragma unroll
  for (int p = 0; p < 4; ++p) {
    int t = t0 + p * 8 + r;
    float s = 0.f;
    if (t < SQ) {
      size_t src = (size_t)t * 1024 + 512 + v0 + c;
      #pragma unroll
      for (int z = 0; z < 4; ++z) s += kvp[(size_t)z * (SQ * 1024) + src];
    }
    tile[p * 8 + r][c] = s;
  }
  __syncthreads();
  #pragma unroll
  for (int p = 0; p < 4; ++p) {
    int v = v0 + p * 8 + r;
    vt[(size_t)v * 1024 + t0 + c] = f2bf(tile[c][p * 8 + r]);
  }
}

// ======================= f32 -> bf16 convert =======================
__global__ void k_f2b(const float* __restrict__ in, ushort_t* __restrict__ out, int n) {
  int i = (blockIdx.x * blockDim.x + threadIdx.x) * 4;
  if (i >= n) return;
  float4 v = *reinterpret_cast<const float4*>(in + i);
  uint2 pk;
  pk.x = (uint32_t)f2bf(v.x) | ((uint32_t)f2bf(v.y) << 16);
  pk.y = (uint32_t)f2bf(v.z) | ((uint32_t)f2bf(v.w) << 16);
  *reinterpret_cast<uint2*>(out + i) = pk;
}

// akv[r][c] = bf16( c<2048 ? prevh[r][c] : hidden[r][c-2048] )
__global__ void k_concat_b(const float* __restrict__ prevh, const float* __restrict__ hidden,
                           ushort_t* __restrict__ out) {
  int i = (blockIdx.x * blockDim.x + threadIdx.x) * 4;
  if (i >= SQ * 4096) return;
  int r = i >> 12, c = i & 4095;
  const float* src = (c < 2048) ? (prevh + (size_t)r * 2048 + c)
                                : (hidden + (size_t)r * 2048 + (c - 2048));
  float4 v = *reinterpret_cast<const float4*>(src);
  uint2 pk;
  pk.x = (uint32_t)f2bf(v.x) | ((uint32_t)f2bf(v.y) << 16);
  pk.y = (uint32_t)f2bf(v.z) | ((uint32_t)f2bf(v.w) << 16);
  *reinterpret_cast<uint2*>(out + (size_t)r * 4096 + c) = pk;
}

// ======================= transpose + convert: W [K][N] f32 -> Wt [N][K] bf16 ======
__global__ __launch_bounds__(256)
void k_tconv(const float* __restrict__ in, ushort_t* __restrict__ out, int K, int N) {
  __shared__ float t[32][33];
  int n0 = blockIdx.x * 32, k0 = blockIdx.y * 32;
  int r = threadIdx.x >> 5, c = threadIdx.x & 31;
  #pragma unroll
  for (int p = 0; p < 4; ++p)
    t[p * 8 + r][c] = in[(size_t)(k0 + p * 8 + r) * N + n0 + c];
  __syncthreads();
  #pragma unroll
  for (int p = 0; p < 4; ++p)
    out[(size_t)(n0 + p * 8 + r) * K + k0 + c] = f2bf(t[c][p * 8 + r]);
}

// ======== bf16 MFMA GEMM, 128x128 tile, BK=32, 2-phase double-buffered LDS ===
// C[M][N] f32 = A[M][Kd] @ Bt[N][Kd] bf16. 4 waves (2x2), wave 64x64 (4x4 frags).
// T3-minimum schedule: STAGE(next) issued BEFORE compute(cur); ONE barrier/step.
__global__ __launch_bounds__(256)
void k_gemm2ph(const ushort_t* __restrict__ A, const ushort_t* __restrict__ Bt,
               float* __restrict__ C, int M, int N, int Kd)
{
  __shared__ __align__(16) ushort_t As[2][128 * 32];
  __shared__ __align__(16) ushort_t Bs[2][128 * 32];

  const int tid  = threadIdx.x;
  const int lane = tid & 63;
  const int w    = tid >> 6;
  const int wm   = w >> 1, wn = w & 1;
  const int fr   = lane & 15;            // frag row (A) / col (B)
  const int kg   = (lane >> 4) * 8;      // frag k base
  const int m0   = blockIdx.y * 128, n0 = blockIdx.x * 128;

  const int lrow = lane >> 2;            // staging row within chunk
  const int lk   = (lane & 3) * 8;       // staging k elements

  f32x4 acc[4][4];
  #pragma unroll
  for (int i = 0; i < 4; ++i)
    #pragma unroll
    for (int j = 0; j < 4; ++j) acc[i][j] = (f32x4){0.f, 0.f, 0.f, 0.f};

  // STAGE: global -> LDS buffer b, K-offset k0 (wave-uniform LDS dest, m97 layout)
  auto STAGE = [&](int b, int k0) {
    #pragma unroll
    for (int c = 0; c < 2; ++c) {
      int ch  = w + c * 4;               // chunk 0..7 -> rows [ch*16, ch*16+16)
      int row = ch * 16 + lrow;
      const ushort_t* ga = A  + (size_t)(m0 + row) * Kd + k0 + lk;
      const ushort_t* gb = Bt + (size_t)(n0 + row) * Kd + k0 + lk;
      __builtin_amdgcn_global_load_lds(
          (const __attribute__((address_space(1))) void*)ga,
          (__attribute__((address_space(3))) void*)(&As[b][0] + ch * 512), 16, 0, 0);
      __builtin_amdgcn_global_load_lds(
          (const __attribute__((address_space(1))) void*)gb,
          (__attribute__((address_space(3))) void*)(&Bs[b][0] + ch * 512), 16, 0, 0);
    }
  };

  const int nt = Kd / 32;
  STAGE(0, 0);
  __syncthreads();

  int cur = 0;
  for (int t = 0; t < nt; ++t) {
    if (t + 1 < nt) STAGE(cur ^ 1, (t + 1) * 32);   // prefetch overlaps compute

    bf16x8 av[4], bv[4];
    #pragma unroll
    for (int mi = 0; mi < 4; ++mi)
      av[mi] = *reinterpret_cast<const bf16x8*>(&As[cur][0] + (wm * 64 + mi * 16 + fr) * 32 + kg);
    #pragma unroll
    for (int nj = 0; nj < 4; ++nj)
      bv[nj] = *reinterpret_cast<const bf16x8*>(&Bs[cur][0] + (wn * 64 + nj * 16 + fr) * 32 + kg);
    #pragma unroll
    for (int mi = 0; mi < 4; ++mi)
      #pragma unroll
      for (int nj = 0; nj < 4; ++nj)
        acc[mi][nj] = __builtin_amdgcn_mfma_f32_16x16x32_bf16(av[mi], bv[nj], acc[mi][nj], 0, 0, 0);

    __syncthreads();                                 // drains vmcnt -> next buf ready
    cur ^= 1;
  }

  // C/D layout: col = lane&15, row = (lane>>4)*4 + r
  #pragma unroll
  for (int mi = 0; mi < 4; ++mi) {
    #pragma unroll
    for (int nj = 0; nj < 4; ++nj) {
      int rbase = m0 + wm * 64 + mi * 16 + (lane >> 4) * 4;
      int col   = n0 + wn * 64 + nj * 16 + fr;
      #pragma unroll
      for (int r = 0; r < 4; ++r) {
        int gr = rbase + r;
        if (gr < M) C[(size_t)gr * N + col] = acc[mi][nj][r];
      }
    }
  }
}

// ======================= bf16 MFMA GEMM, 64x128 tile (GEMM2 split-K) =========
__global__ __launch_bounds__(256)
void k_gemm64(const ushort_t* __restrict__ A, const ushort_t* __restrict__ Bt,
              float* __restrict__ C, int M, int N, int Kd, int kLen)
{
  __shared__ __align__(16) ushort_t As[64 * 32];
  __shared__ __align__(16) ushort_t Bs[128 * 32];

  const int tid  = threadIdx.x;
  const int lane = tid & 63;
  const int w    = tid >> 6;
  const int wm   = w >> 1, wn = w & 1;
  const int fr   = lane & 15;
  const int kg   = (lane >> 4) * 8;
  const int g4   = lane >> 4;
  const int l15  = lane & 15;
  const int m0   = blockIdx.y * 64, n0 = blockIdx.x * 128;
  const int kOff = blockIdx.z * kLen;
  C += (size_t)blockIdx.z * M * N;

  const int arow = tid >> 2, aslot = (tid & 3) * 8;

  f32x4 acc[2][4];
  #pragma unroll
  for (int i = 0; i < 2; ++i)
    #pragma unroll
    for (int j = 0; j < 4; ++j) acc[i][j] = (f32x4){0.f, 0.f, 0.f, 0.f};

  for (int k0 = kOff; k0 < kOff + kLen; k0 += 32) {
    {
      const ushort_t* ga = A + (size_t)(m0 + arow) * Kd + k0 + aslot;
      __builtin_amdgcn_global_load_lds(
          (const __attribute__((address_space(1))) void*)ga,
          (__attribute__((address_space(3))) void*)(As + w * 512), 16, 0, 0);
    }
    #pragma unroll
    for (int c = 0; c < 2; ++c) {
      int u = c * 256 + tid;
      const ushort_t* gb = Bt + (size_t)(n0 + (u >> 2)) * Kd + k0 + (u & 3) * 8;
      __builtin_amdgcn_global_load_lds(
          (const __attribute__((address_space(1))) void*)gb,
          (__attribute__((address_space(3))) void*)(Bs + (c * 256 + w * 64) * 8), 16, 0, 0);
    }
    __syncthreads();

    bf16x8 av[2], bv[4];
    #pragma unroll
    for (int mi = 0; mi < 2; ++mi)
      av[mi] = *reinterpret_cast<const bf16x8*>(As + (wm * 32 + mi * 16 + fr) * 32 + kg);
    #pragma unroll
    for (int nj = 0; nj < 4; ++nj)
      bv[nj] = *reinterpret_cast<const bf16x8*>(Bs + (wn * 64 + nj * 16 + fr) * 32 + kg);
    #pragma unroll
    for (int mi = 0; mi < 2; ++mi)
      #pragma unroll
      for (int nj = 0; nj < 4; ++nj)
        acc[mi][nj] = __builtin_amdgcn_mfma_f32_16x16x32_bf16(av[mi], bv[nj], acc[mi][nj], 0, 0, 0);
    __syncthreads();
  }

  #pragma unroll
  for (int mi = 0; mi < 2; ++mi) {
    #pragma unroll
    for (int nj = 0; nj < 4; ++nj) {
      int rbase = m0 + wm * 32 + mi * 16 + g4 * 4;
      int col   = n0 + wn * 64 + nj * 16 + l15;
      #pragma unroll
      for (int r = 0; r < 4; ++r) {
        int gr = rbase + r;
        if (gr < M) C[(size_t)gr * N + col] = acc[mi][nj][r];
      }
    }
  }
}

// ======================= MFMA flash attention =======================
// grid (80, 16): x = g*16+h, y -> qt = 15 - y (heavy first). 256 thr = 4 waves.
__global__ __launch_bounds__(256)
void k_attn_mfma(const ushort_t* __restrict__ qb, const ushort_t* __restrict__ kb,
                 const ushort_t* __restrict__ vt, ushort_t* __restrict__ oattb)
{
  __shared__ __align__(16) ushort_t Ks[64 * 128];   // [kv][128 d], slot s holds d-slot s^(kv&7)
  __shared__ __align__(16) ushort_t Vs[128 * 64];   // [d][64 kv], slot s holds kv-slot s^(d&7)
  __shared__ __align__(16) ushort_t Ps[4][16 * 64]; // per-wave P [16 q][64 kv], swizzled

  const int tid  = threadIdx.x;
  const int lane = tid & 63;
  const int w    = tid >> 6;
  const int l15  = lane & 15;
  const int g4   = lane >> 4;
  const int gh   = blockIdx.x;
  const int g = gh >> 4, h = gh & 15, kvh = (gh & 15) >> 2;
  const int qt = 15 - blockIdx.y;
  const int t0 = qt * 64;

  bf16x8 av[4];
  {
    int t = t0 + w * 16 + l15;
    const ushort_t* qrow = qb + (((size_t)(g * SQ + t)) * 16 + h) * 128;
    #pragma unroll
    for (int kk = 0; kk < 4; ++kk)
      av[kk] = *reinterpret_cast<const bf16x8*>(qrow + kk * 32 + g4 * 8);
  }

  f32x4 acc[8];
  #pragma unroll
  for (int dt = 0; dt < 8; ++dt) acc[dt] = (f32x4){0.f, 0.f, 0.f, 0.f};
  float m[4], l[4];
  #pragma unroll
  for (int r = 0; r < 4; ++r) { m[r] = -1e30f; l[r] = 0.f; }

  ushort_t* pw = &Ps[w][0];

  for (int jt = 0; jt <= qt; ++jt) {
    int u0 = jt * 64;
    #pragma unroll
    for (int i = 0; i < 4; ++i) {
      int c = (w * 4 + i) * 64 + lane;
      int kv = c >> 4, sl = c & 15;
      const ushort_t* srck = kb + (size_t)(u0 + kv) * 512 + kvh * 128 + ((sl ^ (kv & 7)) << 3);
      __builtin_amdgcn_global_load_lds(
          (const __attribute__((address_space(1))) void*)srck,
          (__attribute__((address_space(3))) void*)(Ks + (w * 4 + i) * 512), 16, 0, 0);
      int d = c >> 3, sv = c & 7;
      const ushort_t* srcv = vt + (size_t)(kvh * 128 + d) * 1024 + u0 + ((sv ^ (d & 7)) << 3);
      __builtin_amdgcn_global_load_lds(
          (const __attribute__((address_space(1))) void*)srcv,
          (__attribute__((address_space(3))) void*)(Vs + (w * 4 + i) * 512), 16, 0, 0);
    }
    __syncthreads();

    f32x4 S[4];
    #pragma unroll
    for (int ct = 0; ct < 4; ++ct) S[ct] = (f32x4){0.f, 0.f, 0.f, 0.f};
    #pragma unroll
    for (int ct = 0; ct < 4; ++ct) {
      int kv = ct * 16 + l15;
      #pragma unroll
      for (int kk = 0; kk < 4; ++kk) {
        bf16x8 bv = *reinterpret_cast<const bf16x8*>(
            Ks + kv * 128 + ((((kk << 2) | g4) ^ (kv & 7)) << 3));
        S[ct] = __builtin_amdgcn_mfma_f32_16x16x32_bf16(av[kk], bv, S[ct], 0, 0, 0);
      }
    }
    if (jt == qt) {
      #pragma unroll
      for (int ct = 0; ct < 4; ++ct) {
        int u = u0 + ct * 16 + l15;
        #pragma unroll
        for (int r = 0; r < 4; ++r) {
          int t = t0 + w * 16 + g4 * 4 + r;
          if (u > t) S[ct][r] = -1e30f;
        }
      }
    }
    // tile max per row
    float tm[4];
    #pragma unroll
    for (int r = 0; r < 4; ++r) {
      float t1 = fmaxf(fmaxf(S[0][r], S[1][r]), fmaxf(S[2][r], S[3][r]));
      t1 = fmaxf(t1, __shfl_xor(t1, 1));
      t1 = fmaxf(t1, __shfl_xor(t1, 2));
      t1 = fmaxf(t1, __shfl_xor(t1, 4));
      t1 = fmaxf(t1, __shfl_xor(t1, 8));
      tm[r] = t1;
    }
    // defer-max (T13): only rescale when some row grew past m + 8
    bool need = (tm[0] > m[0] + 8.f) || (tm[1] > m[1] + 8.f) ||
                (tm[2] > m[2] + 8.f) || (tm[3] > m[3] + 8.f);
    if (__any(need)) {
      #pragma unroll
      for (int r = 0; r < 4; ++r) {
        float mn = fmaxf(m[r], tm[r]);
        float corr = __expf(m[r] - mn);
        m[r] = mn;
        l[r] *= corr;
        #pragma unroll
        for (int dt = 0; dt < 8; ++dt) acc[dt][r] *= corr;
      }
    }
    #pragma unroll
    for (int r = 0; r < 4; ++r) {
      float ps = 0.f;
      #pragma unroll
      for (int ct = 0; ct < 4; ++ct) {
        float p = __expf(S[ct][r] - m[r]);
        S[ct][r] = p;
        ps += p;
      }
      ps += __shfl_xor(ps, 1);
      ps += __shfl_xor(ps, 2);
      ps += __shfl_xor(ps, 4);
      ps += __shfl_xor(ps, 8);
      l[r] += ps;
    }

    #pragma unroll
    for (int ct = 0; ct < 4; ++ct) {
      int kv = ct * 16 + l15;
      #pragma unroll
      for (int r = 0; r < 4; ++r) {
        int q = g4 * 4 + r;
        pw[q * 64 + ((((kv >> 3) ^ (q & 7)) << 3) | (kv & 7))] = f2bf_fast(S[ct][r]);
      }
    }
    #pragma unroll
    for (int kk = 0; kk < 2; ++kk) {
      bf16x8 pa = *reinterpret_cast<const bf16x8*>(
          pw + l15 * 64 + ((((kk << 2) | g4) ^ (l15 & 7)) << 3));
      #pragma unroll
      for (int dt = 0; dt < 8; ++dt) {
        int d = dt * 16 + l15;
        bf16x8 vv = *reinterpret_cast<const bf16x8*>(
            Vs + d * 64 + ((((kk << 2) | g4) ^ (d & 7)) << 3));
        acc[dt] = __builtin_amdgcn_mfma_f32_16x16x32_bf16(pa, vv, acc[dt], 0, 0, 0);
      }
    }
    __syncthreads();
  }

  #pragma unroll
  for (int r = 0; r < 4; ++r) {
    int t = t0 + w * 16 + g4 * 4 + r;
    if (t >= SQ) continue;
    float inv = 1.f / l[r];
    ushort_t* dst = oattb + ((size_t)(g * SQ + t)) * 2048 + h * 128;
    #pragma unroll
    for (int dt = 0; dt < 8; ++dt)
      dst[dt * 16 + l15] = f2bf_fast(acc[dt][r] * inv);
  }
}

// ======================= launch =======================
extern "C" void kernel_launch(void* const* d_in, const int* in_sizes, int n_in,
                              void* d_out, int out_size, void* d_ws, size_t ws_size,
                              hipStream_t stream) {
  const float* hidden = (const float*)d_in[0];   // (1024, 2048)
  const float* prevh  = (const float*)d_in[1];   // (1023, 2048)
  const float* Wq     = (const float*)d_in[4];   // (2048, 10240)
  const float* Wkv    = (const float*)d_in[5];   // (4096, 1024)
  const float* Wo     = (const float*)d_in[6];   // (2048, 2048)
  float* out = (float*)d_out;                    // (5115, 2048)

  char* ws = (char*)d_ws;
  float*    kvp   = (float*)ws;                        ws += (size_t)4 * SQ * 1024 * 4;
  float*    cosT  = (float*)ws;                        ws += (size_t)65472 * 4;
  float*    sinT  = (float*)ws;                        ws += (size_t)65472 * 4;
  ushort_t* qbb   = (ushort_t*)ws;                     ws += (size_t)5120 * 2048 * 2;
  ushort_t* kb    = (ushort_t*)ws;                     ws += (size_t)1024 * 512 * 2;
  ushort_t* vtb   = (ushort_t*)ws;                     ws += (size_t)512 * 1024 * 2;
  ushort_t* hbf   = (ushort_t*)ws;                     ws += (size_t)1024 * 2048 * 2;
  ushort_t* akv   = (ushort_t*)ws;                     ws += (size_t)1024 * 4096 * 2;
  ushort_t* oattb = (ushort_t*)ws;                     ws += (size_t)5120 * 2048 * 2;
  ushort_t* wqt   = (ushort_t*)ws;                     ws += (size_t)10240 * 2048 * 2;
  ushort_t* wkvt  = (ushort_t*)ws;                     ws += (size_t)1024 * 4096 * 2;
  ushort_t* wot   = (ushort_t*)ws;                     ws += (size_t)2048 * 2048 * 2;

  float* qp = out;   // f32 q_proj scratch lives in d_out (1023*10240 elements, exact fit)

  k_tables<<<dim3((SQ * 64 + 255) / 256), dim3(256), 0, stream>>>(cosT, sinT);

  // weight transpose+convert
  k_tconv<<<dim3(NQC / 32, HIDC / 32), dim3(256), 0, stream>>>(Wq, wqt, HIDC, NQC);
  k_tconv<<<dim3(NKVC / 32, 4096 / 32), dim3(256), 0, stream>>>(Wkv, wkvt, 4096, NKVC);
  k_tconv<<<dim3(HIDC / 32, HIDC / 32), dim3(256), 0, stream>>>(Wo, wot, HIDC, HIDC);

  // A-matrix converts
  k_f2b<<<dim3((SQ * 2048 / 4 + 255) / 256), dim3(256), 0, stream>>>(hidden + 2048, hbf, SQ * 2048);
  k_concat_b<<<dim3((SQ * 4096 / 4 + 255) / 256), dim3(256), 0, stream>>>(prevh, hidden, akv);

  // q_proj = hidden[1:] @ Wq   (2-phase dbuf, 640 blocks)
  k_gemm2ph<<<dim3(NQC / 128, 8), dim3(256), 0, stream>>>(hbf, wqt, qp, SQ, NQC, 2048);
  // kv = concat(prev,hidden) @ Wkv, split-K x4 (512 blocks)
  k_gemm64<<<dim3(NKVC / 128, 16, 4), dim3(256), 0, stream>>>(akv, wkvt, kvp, SQ, NKVC, 4096, 1024);

  // rope + bf16 pack (rope_k / vtrans fold the 4 kv partials)
  k_rope_q<<<dim3((5115 * 16 * 64 + 255) / 256), dim3(256), 0, stream>>>(qp, qbb, cosT, sinT);
  k_rope_k<<<dim3((SQ * 4 * 64 + 255) / 256), dim3(256), 0, stream>>>(kvp, kb, cosT, sinT);
  k_vtrans<<<dim3(16, 32), dim3(256), 0, stream>>>(kvp, vtb);

  // MFMA flash attention -> bf16 O
  k_attn_mfma<<<dim3(80, 16), dim3(256), 0, stream>>>(qbb, kb, vtb, oattb);

  // out = O_att @ Wo   (2-phase dbuf, 640 blocks)
  k_gemm2ph<<<dim3(HIDC / 128, 40), dim3(256), 0, stream>>>(oattb, wot, out, 5115, HIDC, 2048);
}